// Round 1
// 1049.318 us; speedup vs baseline: 1.0469x; 1.0469x over previous
//
#include <hip/hip_runtime.h>
#include <cstdint>
#include <cstddef>

#define F_IN  512
#define F_HID 256
#define F_OUT 40
#define F_OUTP 48   // padded to 3x16 MFMA tiles

#define HBINS 16384        // 64 KB LDS histogram bins
#define HSLICES 36         // edge slices for hist/place passes

typedef short  bf16x8 __attribute__((ext_vector_type(8)));
typedef float  f32x4  __attribute__((ext_vector_type(4)));
typedef float  f32x2  __attribute__((ext_vector_type(2)));

__device__ __forceinline__ ushort f2b(float f) {   // fp32 -> bf16 RNE
    uint u = __float_as_uint(f);
    return (ushort)((u + 0x7FFFu + ((u >> 16) & 1u)) >> 16);
}
__device__ __forceinline__ uint pack2(float a, float b) {
    return (uint)f2b(a) | ((uint)f2b(b) << 16);
}
__device__ __forceinline__ float b2f(ushort u) {
    return __uint_as_float(((uint)u) << 16);
}

// ---------------------------------------------------------------------------
// Degree histogram WITHOUT global atomics: block (slice s, range r, array a)
// scans its edge slice, counts indices in [r*HBINS, r*HBINS+HBINS) into an LDS
// histogram, writes the 64 KB partial to scratch non-atomically.
// ---------------------------------------------------------------------------

__global__ __launch_bounds__(1024) void hist_kernel(const int* __restrict__ ei,
                                                    int* __restrict__ part,
                                                    int E, int NR) {
    __shared__ int hist[HBINS];
    const int tid = threadIdx.x;
    const int s = blockIdx.x;
    const int r = blockIdx.y;
    const int a = blockIdx.z;
    const int* src = ei + (size_t)a * E;   // a=0: row, a=1: col
    const uint base = (uint)r * HBINS;

    for (int i = tid; i < HBINS; i += 1024) hist[i] = 0;
    __syncthreads();

    int elen  = (E + HSLICES - 1) / HSLICES;
    int start = s * elen;
    int end   = min(start + elen, E);
    for (int i = start + tid; i < end; i += 1024) {
        uint b = (uint)src[i] - base;
        if (b < HBINS) atomicAdd(&hist[b], 1);
    }
    __syncthreads();

    int* dst = part + ((size_t)(a * NR + r) * HSLICES + s) * HBINS;
    for (int i = tid; i < HBINS; i += 1024) dst[i] = hist[i];
}

// Sum the HSLICES partials per (array, node). a=0 -> cnt_row; a=1 -> dinv.
__global__ void hist_reduce(const int* __restrict__ part,
                            int* __restrict__ cnt_row,
                            float* __restrict__ dinv, int N, int NR) {
    int t = blockIdx.x * blockDim.x + threadIdx.x;
    if (t >= 2 * N) return;
    int a = (t >= N) ? 1 : 0;
    int i = t - a * N;
    int r = i >> 14;             // / HBINS
    int bin = i & (HBINS - 1);
    const int* p = part + ((size_t)(a * NR + r) * HSLICES) * HBINS + bin;
    int sum = 0;
#pragma unroll 4
    for (int s = 0; s < HSLICES; ++s) sum += p[(size_t)s * HBINS];
    if (a == 0) cnt_row[i] = sum;
    else        dinv[i] = rsqrtf((float)(sum + 1));
}

// ---------------------------------------------------------------------------
// Single-block exclusive scan of cnt_row -> rowptr[N+1].
// ---------------------------------------------------------------------------

__global__ __launch_bounds__(1024) void scan_kernel(const int* __restrict__ cnt,
                                                    int* __restrict__ rowptr, int N) {
    __shared__ int sums[1024];
    int tid = threadIdx.x;
    int chunk = (N + 1023) >> 10;
    int s0 = tid * chunk;
    int s1 = s0 + chunk;
    if (s0 > N) s0 = N;
    if (s1 > N) s1 = N;
    int sum = 0;
    for (int i = s0; i < s1; ++i) sum += cnt[i];
    sums[tid] = sum;
    __syncthreads();
    for (int off = 1; off < 1024; off <<= 1) {
        int v = (tid >= off) ? sums[tid - off] : 0;
        __syncthreads();
        sums[tid] += v;
        __syncthreads();
    }
    int base = (tid > 0) ? sums[tid - 1] : 0;
    for (int i = s0; i < s1; ++i) {
        rowptr[i] = base;
        base += cnt[i];
    }
    if (tid == 0) rowptr[N] = sums[1023];
}

// ---------------------------------------------------------------------------
// offs[r][s][bin] = rowptr[node] + sum_{s'<s} part[a=0][r][s'][bin].
// One thread per node; per-s writes are lane-consecutive -> coalesced.
// ---------------------------------------------------------------------------

__global__ void slice_scan(const int* __restrict__ part,
                           const int* __restrict__ rowptr,
                           int* __restrict__ offs, int N, int NR) {
    int i = blockIdx.x * blockDim.x + threadIdx.x;
    if (i >= NR * HBINS) return;
    int r = i >> 14;
    int bin = i & (HBINS - 1);
    int acc = (i < N) ? rowptr[i] : 0;
    const int* p = part + ((size_t)r * HSLICES) * HBINS + bin;   // a=0 block
    int* o = offs + ((size_t)r * HSLICES) * HBINS + bin;
    for (int s = 0; s < HSLICES; ++s) {
        o[(size_t)s * HBINS] = acc;
        acc += p[(size_t)s * HBINS];
    }
}

// ---------------------------------------------------------------------------
// CSR placement with LDS cursors only (no global atomics). Block (s, r) loads
// its offset slab into LDS, re-scans its edge slice, places in-range edges.
// ---------------------------------------------------------------------------

__global__ __launch_bounds__(1024) void place_kernel(const int* __restrict__ ei,
                                                     const float* __restrict__ dinv,
                                                     const int* __restrict__ offs,
                                                     uint2* __restrict__ edge_s,
                                                     int E, int NR) {
    __shared__ int cur[HBINS];
    const int tid = threadIdx.x;
    const int s = blockIdx.x;
    const int r = blockIdx.y;
    const int* row = ei;
    const int* col = ei + E;
    const uint base = (uint)r * HBINS;
    const int* oslab = offs + ((size_t)r * HSLICES + s) * HBINS;

    for (int i = tid; i < HBINS; i += 1024) cur[i] = oslab[i];
    __syncthreads();

    int elen  = (E + HSLICES - 1) / HSLICES;
    int start = s * elen;
    int end   = min(start + elen, E);
    for (int i = start + tid; i < end; i += 1024) {
        uint b = (uint)row[i] - base;
        if (b < HBINS) {
            int pos = atomicAdd(&cur[b], 1);
            int c = col[i];
            uint2 v;
            v.x = (uint)c;
            v.y = __float_as_uint(dinv[base + b] * dinv[c]);
            edge_s[pos] = v;
        }
    }
}

// ---------------------------------------------------------------------------
// Weight prep: W1T [256][512] bf16 (= W1^T), W2T [48][256] bf16 (rows 40..47=0).
// ---------------------------------------------------------------------------

__global__ void prep_weights(const float* __restrict__ W1, const float* __restrict__ W2,
                             ushort* __restrict__ W1T, ushort* __restrict__ W2T) {
    int t = blockIdx.x * blockDim.x + threadIdx.x;
    if (t < F_HID * F_IN) {
        int n = t >> 9, k = t & 511;
        W1T[t] = f2b(W1[(size_t)k * F_HID + n]);
        return;
    }
    int u = t - F_HID * F_IN;
    if (u < F_OUTP * F_HID) {
        int n = u >> 8, k = u & 255;
        W2T[u] = f2b((n < F_OUT) ? W2[(size_t)k * F_OUT + n] : 0.f);
    }
}

// ---------------------------------------------------------------------------
// GEMM1 (MFMA bf16): h[M,256] = x[M,512] @ W1.  BM=64, BN=256, BK=32.
// Output h is stored as fp8 e4m3 (1 B/feature) — it is only consumed by
// prop1's random gathers, which are at the vector-load BW ceiling; fp8
// halves the gathered bytes per edge.
// ---------------------------------------------------------------------------

#define G1_LDK 40

__global__ __launch_bounds__(256) void gemm1_mfma(const float* __restrict__ A,
                                                  const ushort* __restrict__ BT,
                                                  unsigned char* __restrict__ C, int M) {
    __shared__ ushort As[64 * G1_LDK];
    __shared__ ushort Bs[256 * G1_LDK];
    const int tid  = threadIdx.x;
    const int bm   = blockIdx.x * 64;
    const int wave = tid >> 6;
    const int lane = tid & 63;
    const int quad = lane >> 4;
    const int l16  = lane & 15;

    f32x4 acc[4][4] = {};

    const int ar = tid >> 2;
    const int ac = (tid & 3) * 8;

    for (int k0 = 0; k0 < F_IN; k0 += 32) {
        {
            int gr = bm + ar;
            float4 v0 = make_float4(0.f, 0.f, 0.f, 0.f), v1 = v0;
            if (gr < M) {
                const float* ap = A + (size_t)gr * F_IN + k0 + ac;
                v0 = *(const float4*)(ap);
                v1 = *(const float4*)(ap + 4);
            }
            uint4 w;
            w.x = pack2(v0.x, v0.y);
            w.y = pack2(v0.z, v0.w);
            w.z = pack2(v1.x, v1.y);
            w.w = pack2(v1.z, v1.w);
            *(uint4*)&As[ar * G1_LDK + ac] = w;
        }
#pragma unroll
        for (int p = 0; p < 4; ++p) {
            int idx = tid + p * 256;
            int r = idx >> 2;
            int c = (idx & 3) * 8;
            uint4 v = *(const uint4*)(BT + (size_t)r * F_IN + k0 + c);
            *(uint4*)&Bs[r * G1_LDK + c] = v;
        }
        __syncthreads();

        bf16x8 af[4], bfr[4];
#pragma unroll
        for (int mt = 0; mt < 4; ++mt)
            af[mt] = *(bf16x8*)&As[(mt * 16 + l16) * G1_LDK + quad * 8];
#pragma unroll
        for (int nt = 0; nt < 4; ++nt)
            bfr[nt] = *(bf16x8*)&Bs[(wave * 64 + nt * 16 + l16) * G1_LDK + quad * 8];
#pragma unroll
        for (int mt = 0; mt < 4; ++mt)
#pragma unroll
            for (int nt = 0; nt < 4; ++nt)
                acc[mt][nt] = __builtin_amdgcn_mfma_f32_16x16x32_bf16(af[mt], bfr[nt],
                                                                     acc[mt][nt], 0, 0, 0);
        __syncthreads();
    }

#pragma unroll
    for (int mt = 0; mt < 4; ++mt) {
#pragma unroll
        for (int i = 0; i < 4; ++i) {
            int row = bm + mt * 16 + quad * 4 + i;
            if (row < M) {
#pragma unroll
                for (int nt = 0; nt < 4; ++nt) {
                    int col = wave * 64 + nt * 16 + l16;
                    // fp8 e4m3 encode (hw RNE), low byte of the packed result
                    uint pk = (uint)__builtin_amdgcn_cvt_pk_fp8_f32(acc[mt][nt][i], 0.f, 0, false);
                    C[(size_t)row * F_HID + col] = (unsigned char)pk;
                }
            }
        }
    }
}

// ---------------------------------------------------------------------------
// Propagate layer 1 (F=256, fp8 gather) + bias + ReLU. One wave per row;
// masked chunks of 8 keep 8 gathers in flight. h rows are 256 B (fp8), so
// each lane fetches one uint (4 features) and decodes via v_cvt_pk_f32_fp8.
// Halves bytes/edge vs bf16 (520 -> 264) at the measured ~6.4 TB/s
// vector-load ceiling.
// ---------------------------------------------------------------------------

#define P1U 8

__global__ __launch_bounds__(256) void prop1_kernel(const unsigned char* __restrict__ h,
                                                    const float* __restrict__ b1,
                                                    const float* __restrict__ dinv,
                                                    const int* __restrict__ rowptr,
                                                    const uint2* __restrict__ edge_s,
                                                    ushort* __restrict__ g, int N) {
    int wid  = (blockIdx.x * blockDim.x + threadIdx.x) >> 6;
    int lane = threadIdx.x & 63;
    if (wid >= N) return;
    const uint* hw = (const uint*)h;
    float di = dinv[wid];
    float sn = di * di;
    uint sv = hw[(size_t)wid * 64 + lane];
    f32x2 s01 = __builtin_amdgcn_cvt_pk_f32_fp8((int)sv, false);
    f32x2 s23 = __builtin_amdgcn_cvt_pk_f32_fp8((int)sv, true);
    float ax = sn * s01.x, ay = sn * s01.y, az = sn * s23.x, aw = sn * s23.y;
    int e0 = rowptr[wid], e1 = rowptr[wid + 1];
    for (int e = e0; e < e1; e += P1U) {
        uint  v[P1U];
        float w[P1U];
#pragma unroll
        for (int u = 0; u < P1U; ++u) {
            int idx = e + u;
            uint2 ev = edge_s[min(idx, e1 - 1)];
            w[u] = (idx < e1) ? __uint_as_float(ev.y) : 0.f;
            v[u] = hw[(size_t)ev.x * 64 + lane];
        }
#pragma unroll
        for (int u = 0; u < P1U; ++u) {
            f32x2 p01 = __builtin_amdgcn_cvt_pk_f32_fp8((int)v[u], false);
            f32x2 p23 = __builtin_amdgcn_cvt_pk_f32_fp8((int)v[u], true);
            ax = fmaf(w[u], p01.x, ax);
            ay = fmaf(w[u], p01.y, ay);
            az = fmaf(w[u], p23.x, az);
            aw = fmaf(w[u], p23.y, aw);
        }
    }
    float4 bv = ((const float4*)b1)[lane];
    ax = fmaxf(ax + bv.x, 0.f);
    ay = fmaxf(ay + bv.y, 0.f);
    az = fmaxf(az + bv.z, 0.f);
    aw = fmaxf(aw + bv.w, 0.f);
    ushort4 o;
    o.x = f2b(ax); o.y = f2b(ay); o.z = f2b(az); o.w = f2b(aw);
    ((ushort4*)(g + (size_t)wid * F_HID))[lane] = o;
}

// ---------------------------------------------------------------------------
// GEMM2 (MFMA bf16): h2[M,40] = g[M,256] @ W2, K fully LDS-staged.
// ---------------------------------------------------------------------------

#define G2_LDK 264

__global__ __launch_bounds__(256) void gemm2_mfma(const ushort* __restrict__ G,
                                                  const ushort* __restrict__ BT,
                                                  ushort* __restrict__ H2, int M) {
    __shared__ ushort As[64 * G2_LDK];
    __shared__ ushort Bs[F_OUTP * G2_LDK];
    const int tid  = threadIdx.x;
    const int bm   = blockIdx.x * 64;
    const int wave = tid >> 6;
    const int lane = tid & 63;
    const int quad = lane >> 4;
    const int l16  = lane & 15;

#pragma unroll
    for (int p = 0; p < 8; ++p) {
        int idx = tid + p * 256;
        int r = idx >> 5;
        int c = (idx & 31) * 8;
        uint4 v = make_uint4(0, 0, 0, 0);
        int gr = bm + r;
        if (gr < M) v = *(const uint4*)(G + (size_t)gr * F_HID + c);
        *(uint4*)&As[r * G2_LDK + c] = v;
    }
#pragma unroll
    for (int p = 0; p < 6; ++p) {
        int idx = tid + p * 256;
        int r = idx >> 5;
        int c = (idx & 31) * 8;
        uint4 v = *(const uint4*)(BT + (size_t)r * F_HID + c);
        *(uint4*)&Bs[r * G2_LDK + c] = v;
    }
    __syncthreads();

    f32x4 acc[3] = {};
#pragma unroll
    for (int ks = 0; ks < F_HID / 32; ++ks) {
        bf16x8 a = *(bf16x8*)&As[(wave * 16 + l16) * G2_LDK + ks * 32 + quad * 8];
#pragma unroll
        for (int nt = 0; nt < 3; ++nt) {
            bf16x8 b = *(bf16x8*)&Bs[(nt * 16 + l16) * G2_LDK + ks * 32 + quad * 8];
            acc[nt] = __builtin_amdgcn_mfma_f32_16x16x32_bf16(a, b, acc[nt], 0, 0, 0);
        }
    }

#pragma unroll
    for (int i = 0; i < 4; ++i) {
        int row = bm + wave * 16 + quad * 4 + i;
        if (row < M) {
#pragma unroll
            for (int nt = 0; nt < 3; ++nt) {
                int col = nt * 16 + l16;
                if (col < F_OUT)
                    H2[(size_t)row * F_OUT + col] = f2b(acc[nt][i]);
            }
        }
    }
}

// ---------------------------------------------------------------------------
// Propagate layer 2 (F=40, bf16 in) + bias + fused log_softmax.
// ---------------------------------------------------------------------------

#define P2U 8

__global__ __launch_bounds__(256) void prop2_kernel(const ushort* __restrict__ h2,
                                                    const float* __restrict__ b2,
                                                    const float* __restrict__ dinv,
                                                    const int* __restrict__ rowptr,
                                                    const uint2* __restrict__ edge_s,
                                                    float* __restrict__ out, int N) {
    int wid  = (blockIdx.x * blockDim.x + threadIdx.x) >> 6;
    int lane = threadIdx.x & 63;
    if (wid >= N) return;
    int li = (lane < F_OUT) ? lane : 0;
    float di = dinv[wid];
    float sn = di * di;
    float acc = sn * b2f(h2[(size_t)wid * F_OUT + li]);
    int e0 = rowptr[wid], e1 = rowptr[wid + 1];
    for (int e = e0; e < e1; e += P2U) {
        ushort v[P2U];
        float  w[P2U];
#pragma unroll
        for (int u = 0; u < P2U; ++u) {
            int idx = e + u;
            uint2 ev = edge_s[min(idx, e1 - 1)];
            w[u] = (idx < e1) ? __uint_as_float(ev.y) : 0.f;
            v[u] = h2[(size_t)ev.x * F_OUT + li];
        }
#pragma unroll
        for (int u = 0; u < P2U; ++u) acc = fmaf(w[u], b2f(v[u]), acc);
    }
    acc += b2[li];

    float a = (lane < F_OUT) ? acc : -INFINITY;
    float m = a;
#pragma unroll
    for (int o = 32; o; o >>= 1) m = fmaxf(m, __shfl_xor(m, o, 64));
    float ex = (lane < F_OUT) ? expf(acc - m) : 0.f;
    float s = ex;
#pragma unroll
    for (int o = 32; o; o >>= 1) s += __shfl_xor(s, o, 64);
    if (lane < F_OUT) {
        size_t base = (size_t)wid * F_OUT + lane;
        out[base] = acc;
        out[(size_t)N * F_OUT + base] = acc - m - logf(s);
    }
}

// ---------------------------------------------------------------------------
// Launch
// ---------------------------------------------------------------------------

extern "C" void kernel_launch(void* const* d_in, const int* in_sizes, int n_in,
                              void* d_out, int out_size, void* d_ws, size_t ws_size,
                              hipStream_t stream) {
    const float* x  = (const float*)d_in[0];
    const int*   ei = (const int*)d_in[1];
    const float* W1 = (const float*)d_in[2];
    const float* b1 = (const float*)d_in[3];
    const float* W2 = (const float*)d_in[4];
    const float* b2 = (const float*)d_in[5];
    float* out = (float*)d_out;

    const int N = in_sizes[0] / F_IN;
    const int E = in_sizes[1] / 2;
    const int NR = (N + HBINS - 1) / HBINS;

    char* p = (char*)d_ws;
    auto alloc = [&](size_t bytes) -> char* {
        char* q = p;
        p += (bytes + 255) & ~(size_t)255;
        return q;
    };
    int*    cnt_row = (int*)alloc((size_t)N * 4);
    int*    rowptr  = (int*)alloc((size_t)(N + 1) * 4);
    float*  dinv    = (float*)alloc((size_t)N * 4);
    uint2*  edge_s  = (uint2*)alloc((size_t)E * 8);
    int*    part    = (int*)alloc((size_t)2 * NR * HSLICES * HBINS * 4);
    int*    offs    = (int*)alloc((size_t)NR * HSLICES * HBINS * 4);
    ushort* W1T     = (ushort*)alloc((size_t)F_HID * F_IN * 2);
    ushort* W2T     = (ushort*)alloc((size_t)F_OUTP * F_HID * 2);
    unsigned char* h = (unsigned char*)alloc((size_t)N * F_HID);   // fp8 e4m3
    ushort* g       = (ushort*)alloc((size_t)N * F_HID * 2);
    ushort* h2      = (ushort*)alloc((size_t)N * F_OUT * 2);

    dim3 hgrid(HSLICES, NR, 2);
    hist_kernel<<<hgrid, 1024, 0, stream>>>(ei, part, E, NR);
    hist_reduce<<<(2 * N + 255) / 256, 256, 0, stream>>>(part, cnt_row, dinv, N, NR);
    scan_kernel<<<1, 1024, 0, stream>>>(cnt_row, rowptr, N);
    slice_scan<<<(NR * HBINS + 255) / 256, 256, 0, stream>>>(part, rowptr, offs, N, NR);

    dim3 pgrid(HSLICES, NR);
    place_kernel<<<pgrid, 1024, 0, stream>>>(ei, dinv, offs, edge_s, E, NR);

    int prep_total = F_HID * F_IN + F_OUTP * F_HID;
    prep_weights<<<(prep_total + 255) / 256, 256, 0, stream>>>(W1, W2, W1T, W2T);

    gemm1_mfma<<<(N + 63) / 64, 256, 0, stream>>>(x, W1T, h, N);
    prop1_kernel<<<(N + 3) / 4, 256, 0, stream>>>(h, b1, dinv, rowptr, edge_s, g, N);
    gemm2_mfma<<<(N + 63) / 64, 256, 0, stream>>>(g, W2T, h2, N);
    prop2_kernel<<<(N + 3) / 4, 256, 0, stream>>>(h2, b2, dinv, rowptr, edge_s, out, N);
}